// Round 1
// baseline (3237.044 us; speedup 1.0000x reference)
//
#include <hip/hip_runtime.h>
#include <cstdint>
#include <cstddef>

typedef unsigned int   u32;
typedef unsigned short u16;
typedef unsigned long long u64;
typedef __attribute__((ext_vector_type(8))) short bf16x8;   // 8 bf16 = 4 VGPR
typedef __attribute__((ext_vector_type(4))) float f32x4;

#define B_  512
#define T_  168
#define H_  512

// ---------------- workspace layout (bytes). Requires ws_size >= 16MB --------
#define OFF_U1P   (0u)                    // packed U1   bf16 [16kc][128ng][64][8]  (2MB)
#define OFF_UW2P  (2u*1024*1024)          // packed W2;U2 bf16 [32kc][128ng][64][8] (4MB)
#define OFF_FLAGS (6u*1024*1024)          // flag1[512]*128B ; flag2[512]*128B
#define OFF_TICK  (6u*1024*1024 + 256u*1024)   // ticket[8], gdone at [8]
#define OFF_H1    (8u*1024*1024)          // h1 ring, 8 slots x 512KB (4MB)
#define OFF_H2    (12u*1024*1024)         // h2 ring, 8 slots x 512KB (4MB)
#define H_SLOT    262144u                 // u16 elems per slot = 32bg*16kc*64*8
#define NRING     8
#define FS        32                      // ints per flag slot (128B line)
#define NFLAG     16384                   // ints per flag array (512*FS)
#define SMEM_V8   (131072 + 6144 + 3072)  // B(128K) + hlds(6K) + wlds(3K)

__device__ __forceinline__ u16 f2bf(float v){              // RNE f32->bf16
  u32 u = __float_as_uint(v);
  return (u16)((u + 0x7fffu + ((u >> 16) & 1u)) >> 16);
}
__device__ __forceinline__ float sigm_f(float x){ return __fdividef(1.f, 1.f + __expf(-x)); }
__device__ __forceinline__ float tanh_ff(float x){
  float e = __expf(-2.f*fabsf(x));
  float t = __fdividef(1.f - e, 1.f + e);
  return (x < 0.f) ? -t : t;
}
__device__ __forceinline__ void async_cp16(const void* g, void* l){
  __builtin_amdgcn_global_load_lds((const __attribute__((address_space(1))) u32*)g,
                                   (__attribute__((address_space(3))) u32*)l, 16, 0, 0);
}

// ---------------- v8 memory model -------------------------------------------
// Roles are assigned by REAL XCD (s_getreg XCC_ID + ticket consensus) so each
// recurrence cohort is XCD-resident. Local exchange: plain write-through
// stores land in the XCD L2; consumers poll flags with SE-scope (sc0) loads
// and invalidate only L1 (buffer_inv sc0) before reading ring data with plain
// loads. Cross-XCD paths (h1 -> layer2, backpressure flags) are dual-published
// (plain + sc1 to the same address: producer role is block-static, so the
// dirty local line is always the newest value -> eviction can never regress
// the LLC copy) and read with sc1 (cache-bypassing) ops. If consensus finds a
// non-local cohort, that cohort uniformly takes the proven sc1/LLC path.

__device__ __forceinline__ int ld_sc0(const int* p){       // SE scope: bypass L1, read XCD L2
  int v;
  asm volatile("global_load_dword %0, %1, off sc0\n\ts_waitcnt vmcnt(0)"
               : "=v"(v) : "v"(p) : "memory");
  return v;
}
__device__ __forceinline__ void inv_l1c(){                 // L1-only invalidate
  asm volatile("buffer_inv sc0" ::: "memory");
}
__device__ __forceinline__ void cfence(){                  // compiler/order fence, no cache maint
  __builtin_amdgcn_fence(__ATOMIC_ACQUIRE, "workgroup");
}
__device__ __forceinline__ void drain_vm(){                // release: stores at coherence point
  asm volatile("s_waitcnt vmcnt(0)" ::: "memory");
}
// poll a per-lane flag (act lanes) until all >= target. vlast caches the last
// observed value (flags are monotone) so a satisfied poll costs 0 memory ops.
__device__ __forceinline__ void poll_ge(const int* p, bool act, int target,
                                        bool local, int& vlast){
  if (__all((!act) || (vlast >= target))) return;
  int it = 0;
  while (true){
    int v = 0x7fffffff;
    if (act){
      if (local && ((it & 7) != 7)) v = ld_sc0(p);     // fast local poll
      else v = __hip_atomic_load(p, __ATOMIC_RELAXED, __HIP_MEMORY_SCOPE_AGENT); // LLC truth
    }
    if (__all(v >= target)){ vlast = v; break; }
    it++;
    __builtin_amdgcn_s_sleep(1);
  }
}
template<bool LOCAL>
__device__ __forceinline__ bf16x8 ldh(const u16* p){
  if (LOCAL) return *(const bf16x8*)p;                  // plain: hits XCD L2 (L1 inv'd)
  union { u64 q[2]; bf16x8 v; } u;                      // sc1: LLC, cache-bypassing
  u.q[0] = __hip_atomic_load((const u64*)p,     __ATOMIC_RELAXED, __HIP_MEMORY_SCOPE_AGENT);
  u.q[1] = __hip_atomic_load(((const u64*)p)+1, __ATOMIC_RELAXED, __HIP_MEMORY_SCOPE_AGENT);
  return u.v;
}
__device__ __forceinline__ void st16_dual(u16* p, uint4 v, bool dual){
  u64 lo = ((u64)v.y << 32) | v.x;
  u64 hi = ((u64)v.w << 32) | v.z;
  ((volatile u64*)p)[0] = lo;                           // plain write-through -> XCD L2
  ((volatile u64*)p)[1] = hi;
  if (dual){                                            // sc1 -> LLC (remote readers)
    __hip_atomic_store((u64*)p,     lo, __ATOMIC_RELAXED, __HIP_MEMORY_SCOPE_AGENT);
    __hip_atomic_store(((u64*)p)+1, hi, __ATOMIC_RELAXED, __HIP_MEMORY_SCOPE_AGENT);
  }
}
__device__ __forceinline__ void post_flag(int* p, int v){
  *(volatile int*)p = v;                                // local L2 copy
  __hip_atomic_store(p, v, __ATOMIC_RELAXED, __HIP_MEMORY_SCOPE_AGENT);  // LLC copy
}

// ---------------- weight packing: B-operand fragment layout ------------------
__global__ void pack_w_kernel(const float* __restrict__ U1, const float* __restrict__ W2,
                              const float* __restrict__ U2, u16* __restrict__ U1p,
                              u16* __restrict__ UW2p)
{
  int idx = blockIdx.x*256 + threadIdx.x;
  int ln = idx & 63;
  int q8 = ((ln >> 4) << 3);
  int cl = ln & 15;
  if (idx < 16*128*64) {
    int kc = idx >> 13, ng = (idx >> 6) & 127;
    int row0 = kc*32 + q8, col = ng*16 + cl;
    u16* d = U1p + (size_t)idx*8;
    #pragma unroll
    for (int j=0;j<8;j++) d[j] = f2bf(U1[(size_t)(row0+j)*2048 + col]);
  } else {
    int i2 = idx - 16*128*64;
    if (i2 >= 32*128*64) return;
    int kc = i2 >> 13, ng = (i2 >> 6) & 127;
    int row0 = kc*32 + q8, col = ng*16 + cl;
    u16* d = UW2p + (size_t)i2*8;
    #pragma unroll
    for (int j=0;j<8;j++){
      int r = row0 + j;
      float v = (r < 512) ? W2[(size_t)r*2048 + col] : U2[(size_t)(r-512)*2048 + col];
      d[j] = f2bf(v);
    }
  }
}

__global__ void init_kernel(float* __restrict__ out, const float* __restrict__ fcb,
                            int* __restrict__ flags, int* __restrict__ tick)
{
  int i = blockIdx.x*256 + threadIdx.x;
  if (i < 2*NFLAG) flags[i] = 0;
  if (i < 16) tick[i] = 0;
  if (i < B_*T_) out[i] = fcb[0];
}

// ============================ layer 1 ========================================
// cohort = 16 blocks (bi fixed, hj 0..15), per-wave flags: consumer wave w of
// (bi,hj) needs exactly wave w of all (bi,hj'). No block barrier in the t-loop.
template<bool LOCAL>
__device__ void run_l1(char* smem, int bi, int hj, const float* __restrict__ inp,
                       const float* __restrict__ W1, const float* __restrict__ V,
                       const float* __restrict__ bias, char* __restrict__ ws)
{
  u16*  Bl   = (u16*)smem;                        // [16kc][8ngl][512]
  u16*  hlds = (u16*)(smem + 131072);             // 64 x 40
  float* wlds = (float*)(smem + 131072 + 6144);   // 4*32*6
  constexpr int RS = 40;
  const int tid = threadIdx.x, w = tid>>6, ln = tid&63, col = ln&15, quad = ln>>4;
  const int h0 = hj*32, bg = bi*4 + w;

  const u16* Upak = (const u16*)(ws + OFF_U1P);
  const u16* H1r  = (const u16*)(ws + OFF_H1);
  u16* Hw = (u16*)(ws + OFF_H1);
  int* flag1 = (int*)(ws + OFF_FLAGS);
  int* flag2 = flag1 + NFLAG;

  #pragma unroll
  for (int p=0;p<32;p++){
    int pid = w*32 + p, kc = pid>>3, ngl = pid&7;
    int ng = (ngl>>1)*32 + hj*2 + (ngl&1);
    async_cp16(Upak + ((size_t)(kc*128+ng)*64 + ln)*8, Bl + (size_t)pid*512);
  }
  for (int idx=tid; idx<4*32*6; idx+=256){
    int gate = idx/192, rem = idx%192, hcol = rem/6, k = rem%6;
    int gcol = gate*512 + h0 + hcol;
    wlds[idx] = (k==0)? bias[gcol] : (k<=4 ? V[(size_t)(k-1)*2048 + gcol] : W1[gcol]);
  }

  const int* f1p = flag1 + (size_t)((bi*16 + (ln&15))*4 + w)*FS;            // own cohort
  const int* f2p = flag2 + (size_t)(((bi>>1)*32 + (ln&31))*4 + w)*FS;       // consumers (L2)
  int* myf = flag1 + (size_t)((bi*16 + hj)*4 + w)*FS;
  const bool a16 = ln < 16, a32 = ln < 32;
  int vl_f1 = 0, vl_bp = 0;

  float c[8];
  #pragma unroll
  for (int i=0;i<8;i++) c[i] = 0.f;
  const f32x4 vzero = {0.f,0.f,0.f,0.f};

  __syncthreads();   // one-time: B stage drained + wlds visible

  for (int t=0; t<T_; t++){
    f32x4 acc[8];
    #pragma unroll
    for (int i=0;i<8;i++) acc[i] = vzero;

    if (t > 0){
      poll_ge(f1p, a16, t, LOCAL, vl_f1);           // h1[t-1] complete (wave-w tiles)
      if (LOCAL) inv_l1c(); else cfence();
      const u16* ab = H1r + (size_t)((t-1)&7)*H_SLOT + (size_t)bg*16*512 + (size_t)ln*8;
      bf16x8 aw[8];
      #pragma unroll
      for (int i=0;i<8;i++) aw[i] = ldh<LOCAL>(ab + (size_t)i*512);
      #pragma unroll
      for (int kc=0; kc<16; kc++){
        bf16x8 av = aw[kc&7];
        if (kc < 8) aw[kc&7] = ldh<LOCAL>(ab + (size_t)(kc+8)*512);
        const u16* bb = Bl + (size_t)kc*8*512 + (size_t)ln*8;
        #pragma unroll
        for (int ngl=0; ngl<8; ngl++)
          acc[ngl] = __builtin_amdgcn_mfma_f32_16x16x32_bf16(
              av, *(const bf16x8*)(bb + (size_t)ngl*512), acc[ngl], 0,0,0);
      }
    }

    // epilogue (wave-local)
    float iv[4][5];
    #pragma unroll
    for (int r=0;r<4;r++){
      const float* ip = inp + ((size_t)(bi*64 + w*16 + quad*4 + r)*T_ + t)*5;
      #pragma unroll
      for (int k=0;k<5;k++) iv[r][k] = ip[k];
    }
    #pragma unroll
    for (int hg=0; hg<2; hg++){
      float wv[4][6];
      #pragma unroll
      for (int gate=0; gate<4; gate++){
        const float* wp = wlds + (size_t)(gate*32 + hg*16 + col)*6;
        #pragma unroll
        for (int k=0;k<6;k++) wv[gate][k] = wp[k];
      }
      #pragma unroll
      for (int r=0;r<4;r++){
        float gv[4];
        #pragma unroll
        for (int gate=0; gate<4; gate++){
          gv[gate] = acc[gate*2+hg][r] + wv[gate][0]
                   + iv[r][0]*wv[gate][1] + iv[r][1]*wv[gate][2]
                   + iv[r][2]*wv[gate][3] + iv[r][3]*wv[gate][4]
                   + iv[r][4]*wv[gate][5];
        }
        float ig=sigm_f(gv[0]), fg=sigm_f(gv[1]), gg=tanh_ff(gv[2]), og=sigm_f(gv[3]);
        float cn = fg*c[hg*4+r] + ig*gg;
        c[hg*4+r] = cn;
        hlds[(size_t)(w*16 + quad*4 + r)*RS + hg*16 + col] = f2bf(og*tanh_ff(cn));
      }
    }
    // back-pressure: slot t&7 clobbers h1[t-8]; layer2 must be past step t-8
    if (t >= NRING) poll_ge(f2p, a32, t-NRING+1, false, vl_bp);
    // pack: same-wave transpose via hlds; dual-publish (local L2 + LLC for layer2)
    {
      uint4 v = *(const uint4*)&hlds[(size_t)(w*16 + (ln&15))*RS + (ln>>4)*8];
      u16* dst = Hw + (size_t)(t&7)*H_SLOT + ((size_t)(bg*16 + hj)*64 + ln)*8;
      st16_dual(dst, v, true);
    }
    drain_vm();
    if (ln == 0) post_flag(myf, t+1);
  }
}

// ============================ layer 2 ========================================
template<bool LOC>
__device__ __forceinline__ void l2_half(f32x4* accA, f32x4* accB, const u16* Bh,
                                        const u16* A, int bgA, int bgB, int ln)
{
  const u16* pA = A + (size_t)bgA*16*512 + (size_t)ln*8;
  const u16* pB = A + (size_t)bgB*16*512 + (size_t)ln*8;
  bf16x8 awA[8], awB[8];
  #pragma unroll
  for (int i=0;i<8;i++){
    awA[i] = ldh<LOC>(pA + (size_t)i*512);
    awB[i] = ldh<LOC>(pB + (size_t)i*512);
  }
  #pragma unroll
  for (int kc=0; kc<16; kc++){
    bf16x8 avA = awA[kc&7], avB = awB[kc&7];
    if (kc < 8){
      awA[kc&7] = ldh<LOC>(pA + (size_t)(kc+8)*512);
      awB[kc&7] = ldh<LOC>(pB + (size_t)(kc+8)*512);
    }
    const u16* bb = Bh + (size_t)kc*4*512 + (size_t)ln*8;
    #pragma unroll
    for (int ngl=0; ngl<4; ngl++){
      bf16x8 bf = *(const bf16x8*)(bb + (size_t)ngl*512);
      accA[ngl] = __builtin_amdgcn_mfma_f32_16x16x32_bf16(avA, bf, accA[ngl], 0,0,0);
      accB[ngl] = __builtin_amdgcn_mfma_f32_16x16x32_bf16(avB, bf, accB[ngl], 0,0,0);
    }
  }
}

template<bool LOCAL>
__device__ void run_l2(char* smem, int bi2, int hj, const float* __restrict__ inp,
                       const float* __restrict__ V, const float* __restrict__ bias,
                       const float* __restrict__ fcw, char* __restrict__ ws,
                       float* __restrict__ out)
{
  u16*  Bl   = (u16*)smem;                        // [32kc][4ngl][512]
  u16*  hlds = (u16*)(smem + 131072);             // 128 x 24
  float* wlds = (float*)(smem + 131072 + 6144);   // 4*16*6
  constexpr int RS = 24;
  const int tid = threadIdx.x, w = tid>>6, ln = tid&63, col = ln&15, quad = ln>>4;
  const int h0 = hj*16, bgA = bi2*8 + w, bgB = bgA + 4;

  const u16* Upak = (const u16*)(ws + OFF_UW2P);
  const u16* H1r  = (const u16*)(ws + OFF_H1);
  const u16* H2r  = (const u16*)(ws + OFF_H2);
  u16* Hw = (u16*)(ws + OFF_H2);
  int* flag1 = (int*)(ws + OFF_FLAGS);
  int* flag2 = flag1 + NFLAG;

  #pragma unroll
  for (int p=0;p<32;p++){
    int pid = w*32 + p, kc = pid>>2, ngl = pid&3;
    int ng = ngl*32 + hj;
    async_cp16(Upak + ((size_t)(kc*128+ng)*64 + ln)*8, Bl + (size_t)pid*512);
  }
  for (int idx=tid; idx<4*16*6; idx+=256){
    int gate = idx/96, rem = idx%96, hcol = rem/6, k = rem%6;
    int gcol = gate*512 + h0 + hcol;
    wlds[idx] = (k==0)? bias[gcol] : (k<=4 ? V[(size_t)(k-1)*2048 + gcol] : 0.f);
  }
  const float fcwr = fcw[h0 + col];

  const int* h1f = flag1 + (size_t)(((2*bi2 + ((ln>>4)&1))*16 + (ln&15))*4 + w)*FS;
  const int* h2f = flag2 + (size_t)((bi2*32 + (ln&31))*4 + w)*FS;
  int* myf = flag2 + (size_t)((bi2*32 + hj)*4 + w)*FS;
  const bool a32 = ln < 32;
  int vl_h1 = 0, vl_h2 = 0;

  float c[8];
  #pragma unroll
  for (int i=0;i<8;i++) c[i] = 0.f;
  const f32x4 vzero = {0.f,0.f,0.f,0.f};

  __syncthreads();

  for (int t=0; t<T_; t++){
    f32x4 accA[4], accB[4];
    #pragma unroll
    for (int i=0;i<4;i++){ accA[i] = vzero; accB[i] = vzero; }

    // h1[t] ready (cross-XCD; layer1 runs ahead -> usually register fast-pass)
    poll_ge(h1f, a32, t+1, false, vl_h1);
    cfence();
    const u16* A1 = H1r + (size_t)(t&7)*H_SLOT;
    l2_half<false>(accA, accB, Bl, A1, bgA, bgB, ln);   // feed-forward half first

    if (t > 0){
      poll_ge(h2f, a32, t, LOCAL, vl_h2);               // h2[t-1] (the recurrence edge)
      if (LOCAL) inv_l1c(); else cfence();
      const u16* A2 = H2r + (size_t)((t-1)&7)*H_SLOT;
      l2_half<LOCAL>(accA, accB, Bl + (size_t)16*4*512, A2, bgA, bgB, ln);
    }

    // epilogue
    float wv[4][5];
    #pragma unroll
    for (int gate=0; gate<4; gate++){
      const float* wp = wlds + (size_t)(gate*16 + col)*6;
      #pragma unroll
      for (int k=0;k<5;k++) wv[gate][k] = wp[k];
    }
    float fcp[2][4];
    #pragma unroll
    for (int sel=0; sel<2; sel++){
      const f32x4* ac = sel ? accB : accA;
      #pragma unroll
      for (int r=0;r<4;r++){
        const float* ip = inp + ((size_t)(bi2*128 + sel*64 + w*16 + quad*4 + r)*T_ + t)*5;
        float i0=ip[0], i1=ip[1], i2=ip[2], i3=ip[3];
        float gv[4];
        #pragma unroll
        for (int gate=0; gate<4; gate++){
          gv[gate] = ac[gate][r] + wv[gate][0]
                   + i0*wv[gate][1] + i1*wv[gate][2] + i2*wv[gate][3] + i3*wv[gate][4];
        }
        float ig=sigm_f(gv[0]), fg=sigm_f(gv[1]), gg=tanh_ff(gv[2]), og=sigm_f(gv[3]);
        float cn = fg*c[sel*4+r] + ig*gg;
        c[sel*4+r] = cn;
        float h = og*tanh_ff(cn);
        fcp[sel][r] = h*fcwr;
        hlds[(size_t)(sel*64 + w*16 + quad*4 + r)*RS + col] = f2bf(h);
      }
    }
    // publish h2[t] FIRST (this is the recurrence edge), out-atomics after
    {
      int sel = ln>>5, ch = (ln>>4)&1, m = ln&15;
      uint4 v = *(const uint4*)&hlds[(size_t)(sel*64 + w*16 + m)*RS + ch*8];
      int lp = ((hj&1)*2 + ch)*16 + m;
      int bgx = bi2*8 + sel*4 + w;
      u16* dst = Hw + (size_t)(t&7)*H_SLOT + ((size_t)(bgx*16 + (hj>>1))*64 + lp)*8;
      st16_dual(dst, v, !LOCAL);
    }
    drain_vm();
    if (ln == 0) post_flag(myf, t+1);

    #pragma unroll
    for (int sel=0; sel<2; sel++){
      #pragma unroll
      for (int r=0;r<4;r++){
        float v = fcp[sel][r];
        #pragma unroll
        for (int m=1;m<16;m<<=1) v += __shfl_xor(v, m, 16);
        if (col == 0)
          atomicAdd(&out[(size_t)(bi2*128 + sel*64 + w*16 + quad*4 + r)*T_ + t], v);
      }
    }
  }
}

// ============================ main: XCD consensus + dispatch =================
__global__ void __launch_bounds__(256, 1)
lstm_main_v8(const float* __restrict__ inp, const float* __restrict__ W1,
             const float* __restrict__ V1, const float* __restrict__ b1,
             const float* __restrict__ V2, const float* __restrict__ b2,
             const float* __restrict__ fcw, char* __restrict__ ws, float* __restrict__ out)
{
  extern __shared__ char smem[];
  __shared__ int sh_pos, sh_loc;
  if (threadIdx.x == 0){
    int xcd;
    asm volatile("s_getreg_b32 %0, hwreg(HW_REG_XCC_ID)" : "=s"(xcd));
    xcd &= 7;
    int* tick = (int*)(ws + OFF_TICK);
    int rank = __hip_atomic_fetch_add(&tick[xcd], 1, __ATOMIC_RELAXED, __HIP_MEMORY_SCOPE_AGENT);
    __hip_atomic_fetch_add(&tick[8], 1, __ATOMIC_RELAXED, __HIP_MEMORY_SCOPE_AGENT);
    while (__hip_atomic_load(&tick[8], __ATOMIC_RELAXED, __HIP_MEMORY_SCOPE_AGENT) < 256)
      __builtin_amdgcn_s_sleep(8);
    int cc[8], pref = 0;
    #pragma unroll
    for (int x=0;x<8;x++)
      cc[x] = __hip_atomic_load(&tick[x], __ATOMIC_RELAXED, __HIP_MEMORY_SCOPE_AGENT);
    for (int x=0;x<xcd;x++) pref += cc[x];
    int pos = pref + rank;             // blocks enumerated in (xcd, arrival) order
    int lo, hi;                        // my cohort's position range
    if (pos < 128){ lo = (pos>>4)<<4; hi = lo + 16; }
    else { int q = pos - 128; lo = 128 + ((q>>5)<<5); hi = lo + 32; }
    int xlo = 7, xhi = 7, s = 0;       // xcd of first/last cohort member
    for (int x=0;x<8;x++){ int e = s + cc[x];
      if (lo   >= s && lo   < e) xlo = x;
      if (hi-1 >= s && hi-1 < e) xhi = x;
      s = e; }
    sh_loc = (xlo == xcd && xhi == xcd) ? 1 : 0;
    sh_pos = pos;
  }
  __syncthreads();
  const int pos = sh_pos, loc = sh_loc;
  if (pos < 128){
    if (loc) run_l1<true >(smem, pos>>4, pos&15, inp, W1, V1, b1, ws);
    else     run_l1<false>(smem, pos>>4, pos&15, inp, W1, V1, b1, ws);
  } else {
    int q = pos - 128;
    if (loc) run_l2<true >(smem, q>>5, q&31, inp, V2, b2, fcw, ws, out);
    else     run_l2<false>(smem, q>>5, q&31, inp, V2, b2, fcw, ws, out);
  }
}

extern "C" void kernel_launch(void* const* d_in, const int* in_sizes, int n_in,
                              void* d_out, int out_size, void* d_ws, size_t ws_size,
                              hipStream_t stream) {
  (void)in_sizes; (void)n_in; (void)out_size; (void)ws_size;
  const float* inp = (const float*)d_in[0];
  const float* W1  = (const float*)d_in[1];
  const float* U1  = (const float*)d_in[2];
  const float* V1  = (const float*)d_in[3];
  const float* b1  = (const float*)d_in[4];
  const float* W2  = (const float*)d_in[5];
  const float* U2  = (const float*)d_in[6];
  const float* V2  = (const float*)d_in[7];
  const float* b2  = (const float*)d_in[8];
  const float* fcw = (const float*)d_in[9];
  const float* fcb = (const float*)d_in[10];
  char* ws = (char*)d_ws;
  float* out = (float*)d_out;

  pack_w_kernel<<<1536, 256, 0, stream>>>(U1, W2, U2,
      (u16*)(ws + OFF_U1P), (u16*)(ws + OFF_UW2P));
  init_kernel<<<(B_*T_ + 255)/256, 256, 0, stream>>>(out, fcb,
      (int*)(ws + OFF_FLAGS), (int*)(ws + OFF_TICK));
  (void)hipFuncSetAttribute((const void*)lstm_main_v8,
                            hipFuncAttributeMaxDynamicSharedMemorySize, SMEM_V8);
  lstm_main_v8<<<256, 256, SMEM_V8, stream>>>(inp, W1, V1, b1, V2, b2, fcw, ws, out);
}

// Round 2
// 2221.963 us; speedup vs baseline: 1.4568x; 1.4568x over previous
//
#include <hip/hip_runtime.h>
#include <cstdint>
#include <cstddef>

typedef unsigned int   u32;
typedef unsigned short u16;
typedef unsigned long long u64;
typedef __attribute__((ext_vector_type(8))) short bf16x8;   // 8 bf16 = 4 VGPR
typedef __attribute__((ext_vector_type(4))) float f32x4;

#define B_  512
#define T_  168
#define H_  512

// ---------------- workspace layout (bytes). Requires ws_size >= 16MB --------
#define OFF_U1P   (0u)                    // packed U1   bf16 [16kc][128ng][64][8]  (2MB)
#define OFF_UW2P  (2u*1024*1024)          // packed W2;U2 bf16 [32kc][128ng][64][8] (4MB)
#define OFF_FLAGS (6u*1024*1024)          // flag1[128]*128B ; flag2[128]*128B (32KB)
#define OFF_H1    (8u*1024*1024)          // h1 ring, 8 slots x 512KB (4MB)
#define OFF_H2    (12u*1024*1024)         // h2 ring, 2 slots x 512KB (1MB)
#define H_SLOT    262144u                 // u16 elems per slot = 32bg*16kc*64*8
#define NRING     8
#define FS        32                      // ints per flag slot (128B line)
#define SMEM_V9   (131072 + 6144 + 3072)  // B(128K) + hlds(6K) + wlds(3K)

__device__ __forceinline__ u16 f2bf(float v){              // RNE f32->bf16
  u32 u = __float_as_uint(v);
  return (u16)((u + 0x7fffu + ((u >> 16) & 1u)) >> 16);
}
__device__ __forceinline__ float sigm_f(float x){ return __fdividef(1.f, 1.f + __expf(-x)); }
__device__ __forceinline__ float tanh_ff(float x){
  float e = __expf(-2.f*fabsf(x));
  float t = __fdividef(1.f - e, 1.f + e);
  return (x < 0.f) ? -t : t;
}
__device__ __forceinline__ void async_cp16(const void* g, void* l){
  __builtin_amdgcn_global_load_lds((const __attribute__((address_space(1))) u32*)g,
                                   (__attribute__((address_space(3))) u32*)l, 16, 0, 0);
}

// ---------------- v9 memory model (v7's proven model + per-producer flags) ---
//  - each producer block posts its completed-step count to its OWN 128B flag
//    slot with ONE relaxed sc1 store (no RMW -> no LLC atomic serialization,
//    which was the v7 critical-path suspect: 16-32 fetch_adds to one address
//    per step).
//  - consumers poll all producer flags wave-parallel (lanes 0..15 / 0..31,
//    one load instruction per iteration), with a monotone last-value cache so
//    satisfied polls cost zero memory ops.
//  - ring data freshness: unchanged from v7. Ring stores are relaxed sc1
//    (direct to LLC); plain cached ring reads are fenced by ONE agent-acquire
//    (buffer_inv) per step, ordered for all waves by the block barrier.
//  - L2's h2 half reads A2 with sc1 cache-bypassing loads instead (its poll
//    happens after the per-step inv, so plain loads would be unsafe there).

__device__ __forceinline__ void wpoll(const int* p, bool act, int target, int& vlast){
  if (__all((!act) || (vlast >= target))) return;
  while (true){
    int v = 0x7fffffff;
    if (act) v = __hip_atomic_load(p, __ATOMIC_RELAXED, __HIP_MEMORY_SCOPE_AGENT);
    if (__all(v >= target)){ vlast = v; break; }
    __builtin_amdgcn_s_sleep(1);
  }
}
template<bool PLAIN>
__device__ __forceinline__ bf16x8 ldh(const u16* p){
  if (PLAIN) return *(const bf16x8*)p;                  // cached; freshness via inv+flag
  union { u64 q[2]; bf16x8 v; } u;                      // sc1: LLC, cache-bypassing
  u.q[0] = __hip_atomic_load((const u64*)p,     __ATOMIC_RELAXED, __HIP_MEMORY_SCOPE_AGENT);
  u.q[1] = __hip_atomic_load(((const u64*)p)+1, __ATOMIC_RELAXED, __HIP_MEMORY_SCOPE_AGENT);
  return u.v;
}
__device__ __forceinline__ void ring_st16(u16* p, uint4 v){
  u64 lo = ((u64)v.y << 32) | v.x;
  u64 hi = ((u64)v.w << 32) | v.z;
  __hip_atomic_store((u64*)p,     lo, __ATOMIC_RELAXED, __HIP_MEMORY_SCOPE_AGENT);
  __hip_atomic_store(((u64*)p)+1, hi, __ATOMIC_RELAXED, __HIP_MEMORY_SCOPE_AGENT);
}

// ---------------- weight packing: B-operand fragment layout ------------------
__global__ void pack_w_kernel(const float* __restrict__ U1, const float* __restrict__ W2,
                              const float* __restrict__ U2, u16* __restrict__ U1p,
                              u16* __restrict__ UW2p)
{
  int idx = blockIdx.x*256 + threadIdx.x;
  int ln = idx & 63;
  int q8 = ((ln >> 4) << 3);
  int cl = ln & 15;
  if (idx < 16*128*64) {
    int kc = idx >> 13, ng = (idx >> 6) & 127;
    int row0 = kc*32 + q8, col = ng*16 + cl;
    u16* d = U1p + (size_t)idx*8;
    #pragma unroll
    for (int j=0;j<8;j++) d[j] = f2bf(U1[(size_t)(row0+j)*2048 + col]);
  } else {
    int i2 = idx - 16*128*64;
    if (i2 >= 32*128*64) return;
    int kc = i2 >> 13, ng = (i2 >> 6) & 127;
    int row0 = kc*32 + q8, col = ng*16 + cl;
    u16* d = UW2p + (size_t)i2*8;
    #pragma unroll
    for (int j=0;j<8;j++){
      int r = row0 + j;
      float v = (r < 512) ? W2[(size_t)r*2048 + col] : U2[(size_t)(r-512)*2048 + col];
      d[j] = f2bf(v);
    }
  }
}

__global__ void init_kernel(float* __restrict__ out, const float* __restrict__ fcb,
                            int* __restrict__ flags)
{
  int i = blockIdx.x*256 + threadIdx.x;
  if (i < 256*FS) flags[i] = 0;
  if (i < B_*T_) out[i] = fcb[0];
}

// ============================ layer 1 ========================================
__device__ void run_l1(char* smem, int blk, const float* __restrict__ inp,
                       const float* __restrict__ W1, const float* __restrict__ V,
                       const float* __restrict__ bias, char* __restrict__ ws)
{
  u16*  Bl   = (u16*)smem;                        // [16kc][8ngl][512]
  u16*  hlds = (u16*)(smem + 131072);             // 64 x 40
  float* wlds = (float*)(smem + 131072 + 6144);   // 4*32*6
  constexpr int RS = 40;
  const int tid = threadIdx.x, w = tid>>6, ln = tid&63, col = ln&15, quad = ln>>4;
  const int bi = blk & 7, hj = blk >> 3, h0 = hj*32, bg = bi*4 + w;

  const u16* Upak = (const u16*)(ws + OFF_U1P);
  const u16* H1r  = (const u16*)(ws + OFF_H1);
  u16* Hw = (u16*)(ws + OFF_H1);
  int* flag1 = (int*)(ws + OFF_FLAGS);
  int* flag2 = flag1 + 128*FS;
  const int* f1p = flag1 + (size_t)(bi*16 + (ln&15))*FS;            // own cohort producers
  const int* f2p = flag2 + (size_t)((bi>>1)*32 + (ln&31))*FS;       // L2 consumers (backpressure)
  int* myf = flag1 + (size_t)(bi*16 + hj)*FS;
  const bool a16 = ln < 16, a32 = ln < 32;
  int vl1 = 0, vlbp = 0;

  // stage all of B once (32 pieces/wave x 1KB)
  #pragma unroll
  for (int p=0;p<32;p++){
    int pid = w*32 + p, kc = pid>>3, ngl = pid&7;
    int ng = (ngl>>1)*32 + hj*2 + (ngl&1);
    async_cp16(Upak + ((size_t)(kc*128+ng)*64 + ln)*8, Bl + (size_t)pid*512);
  }
  for (int idx=tid; idx<4*32*6; idx+=256){
    int gate = idx/192, rem = idx%192, hcol = rem/6, k = rem%6;
    int gcol = gate*512 + h0 + hcol;
    wlds[idx] = (k==0)? bias[gcol] : (k<=4 ? V[(size_t)(k-1)*2048 + gcol] : W1[gcol]);
  }

  float c[8];
  #pragma unroll
  for (int i=0;i<8;i++) c[i] = 0.f;
  const f32x4 vzero = {0.f,0.f,0.f,0.f};

  for (int t=0; t<T_; t++){
    if (w == 0){
      if (t > 0)      wpoll(f1p, a16, t, vl1);            // h1[t-1] complete, all 16 producers
      if (t >= NRING) wpoll(f2p, a32, t-NRING+1, vlbp);   // ring back-pressure
      // ONE agent-acquire per step: buffer_inv makes the subsequent PLAIN ring
      // loads (all waves, ordered by the barrier) read fresh LLC data.
      __builtin_amdgcn_fence(__ATOMIC_ACQUIRE, "agent");
    }
    __syncthreads();   // barrier 1 (drains B-stage at t=0; orders inv for all waves)

    f32x4 acc[8];
    #pragma unroll
    for (int i=0;i<8;i++) acc[i] = vzero;

    if (t > 0){
      const u16* ab = H1r + (size_t)((t-1)&7)*H_SLOT + (size_t)bg*16*512 + (size_t)ln*8;
      bf16x8 aw[8];
      #pragma unroll
      for (int i=0;i<8;i++) aw[i] = ldh<true>(ab + (size_t)i*512);
      #pragma unroll
      for (int kc=0; kc<16; kc++){
        bf16x8 av = aw[kc&7];
        if (kc < 8) aw[kc&7] = ldh<true>(ab + (size_t)(kc+8)*512);
        const u16* bb = Bl + (size_t)kc*8*512 + (size_t)ln*8;
        #pragma unroll
        for (int ngl=0; ngl<8; ngl++)
          acc[ngl] = __builtin_amdgcn_mfma_f32_16x16x32_bf16(
              av, *(const bf16x8*)(bb + (size_t)ngl*512), acc[ngl], 0,0,0);
      }
    }

    // epilogue (wave-local)
    float iv[4][5];
    #pragma unroll
    for (int r=0;r<4;r++){
      const float* ip = inp + ((size_t)(bi*64 + w*16 + quad*4 + r)*T_ + t)*5;
      #pragma unroll
      for (int k=0;k<5;k++) iv[r][k] = ip[k];
    }
    #pragma unroll
    for (int hg=0; hg<2; hg++){
      float wv[4][6];
      #pragma unroll
      for (int gate=0; gate<4; gate++){
        const float* wp = wlds + (size_t)(gate*32 + hg*16 + col)*6;
        #pragma unroll
        for (int k=0;k<6;k++) wv[gate][k] = wp[k];
      }
      #pragma unroll
      for (int r=0;r<4;r++){
        float gv[4];
        #pragma unroll
        for (int gate=0; gate<4; gate++){
          gv[gate] = acc[gate*2+hg][r] + wv[gate][0]
                   + iv[r][0]*wv[gate][1] + iv[r][1]*wv[gate][2]
                   + iv[r][2]*wv[gate][3] + iv[r][3]*wv[gate][4]
                   + iv[r][4]*wv[gate][5];
        }
        float ig=sigm_f(gv[0]), fg=sigm_f(gv[1]), gg=tanh_ff(gv[2]), og=sigm_f(gv[3]);
        float cn = fg*c[hg*4+r] + ig*gg;
        c[hg*4+r] = cn;
        hlds[(size_t)(w*16 + quad*4 + r)*RS + hg*16 + col] = f2bf(og*tanh_ff(cn));
      }
    }
    // pack: SAME-WAVE transpose via hlds (no barrier needed before read)
    {
      uint4 v = *(const uint4*)&hlds[(size_t)(w*16 + (ln&15))*RS + (ln>>4)*8];
      ring_st16(Hw + (size_t)(t&7)*H_SLOT + ((size_t)(bg*16 + hj)*64 + ln)*8, v);
    }
    __syncthreads();   // barrier 2: drains all waves' pack stores before release
    if (tid==0){
      __builtin_amdgcn_fence(__ATOMIC_RELEASE, "workgroup");
      __hip_atomic_store(myf, t+1, __ATOMIC_RELAXED, __HIP_MEMORY_SCOPE_AGENT);
    }
  }
}

// ============================ layer 2 ========================================
template<bool PLAIN>
__device__ __forceinline__ void l2_half(f32x4* accA, f32x4* accB, const u16* Bh,
                                        const u16* A, int bgA, int bgB, int ln)
{
  const u16* pA = A + (size_t)bgA*16*512 + (size_t)ln*8;
  const u16* pB = A + (size_t)bgB*16*512 + (size_t)ln*8;
  bf16x8 awA[8], awB[8];
  #pragma unroll
  for (int i=0;i<8;i++){
    awA[i] = ldh<PLAIN>(pA + (size_t)i*512);
    awB[i] = ldh<PLAIN>(pB + (size_t)i*512);
  }
  #pragma unroll
  for (int kc=0; kc<16; kc++){
    bf16x8 avA = awA[kc&7], avB = awB[kc&7];
    if (kc < 8){
      awA[kc&7] = ldh<PLAIN>(pA + (size_t)(kc+8)*512);
      awB[kc&7] = ldh<PLAIN>(pB + (size_t)(kc+8)*512);
    }
    const u16* bb = Bh + (size_t)kc*4*512 + (size_t)ln*8;
    #pragma unroll
    for (int ngl=0; ngl<4; ngl++){
      bf16x8 bf = *(const bf16x8*)(bb + (size_t)ngl*512);
      accA[ngl] = __builtin_amdgcn_mfma_f32_16x16x32_bf16(avA, bf, accA[ngl], 0,0,0);
      accB[ngl] = __builtin_amdgcn_mfma_f32_16x16x32_bf16(avB, bf, accB[ngl], 0,0,0);
    }
  }
}

__device__ void run_l2(char* smem, int blk2, const float* __restrict__ inp,
                       const float* __restrict__ V, const float* __restrict__ bias,
                       const float* __restrict__ fcw, char* __restrict__ ws,
                       float* __restrict__ out)
{
  u16*  Bl   = (u16*)smem;                        // [32kc][4ngl][512]
  u16*  hlds = (u16*)(smem + 131072);             // 128 x 24
  float* wlds = (float*)(smem + 131072 + 6144);   // 4*16*6
  constexpr int RS = 24;
  const int tid = threadIdx.x, w = tid>>6, ln = tid&63, col = ln&15, quad = ln>>4;
  const int bi2 = blk2 & 3, hj = blk2 >> 2, h0 = hj*16;
  const int bgA = bi2*8 + w, bgB = bgA + 4;

  const u16* Upak = (const u16*)(ws + OFF_UW2P);
  const u16* H1r  = (const u16*)(ws + OFF_H1);
  const u16* H2r  = (const u16*)(ws + OFF_H2);
  u16* Hw = (u16*)(ws + OFF_H2);
  int* flag1 = (int*)(ws + OFF_FLAGS);
  int* flag2 = flag1 + 128*FS;
  const int* h1f = flag1 + (size_t)(bi2*32 + (ln&31))*FS;   // L1 cohorts 2bi2,2bi2+1
  const int* h2f = flag2 + (size_t)(bi2*32 + (ln&31))*FS;   // own cohort producers
  int* myf = flag2 + (size_t)(bi2*32 + hj)*FS;
  const bool a32 = ln < 32;
  int vlh1 = 0, vlh2 = 0;

  #pragma unroll
  for (int p=0;p<32;p++){
    int pid = w*32 + p, kc = pid>>2, ngl = pid&3;
    int ng = ngl*32 + hj;
    async_cp16(Upak + ((size_t)(kc*128+ng)*64 + ln)*8, Bl + (size_t)pid*512);
  }
  for (int idx=tid; idx<4*16*6; idx+=256){
    int gate = idx/96, rem = idx%96, hcol = rem/6, k = rem%6;
    int gcol = gate*512 + h0 + hcol;
    wlds[idx] = (k==0)? bias[gcol] : (k<=4 ? V[(size_t)(k-1)*2048 + gcol] : 0.f);
  }
  const float fcwr = fcw[h0 + col];

  float c[8];
  #pragma unroll
  for (int i=0;i<8;i++) c[i] = 0.f;
  const f32x4 vzero = {0.f,0.f,0.f,0.f};

  for (int t=0; t<T_; t++){
    if (w == 0){
      wpoll(h1f, a32, t+1, vlh1);               // h1[t] ready (L1 runs ahead -> cheap)
      __builtin_amdgcn_fence(__ATOMIC_ACQUIRE, "agent");   // once/step buffer_inv
    }
    __syncthreads();   // barrier 1 (drains B-stage at t=0; orders inv for all waves)

    f32x4 accA[4], accB[4];
    #pragma unroll
    for (int i=0;i<4;i++){ accA[i] = vzero; accB[i] = vzero; }

    // feed-forward half FIRST (off the h2 recurrence critical path)
    const u16* A1 = H1r + (size_t)(t&7)*H_SLOT;
    l2_half<true>(accA, accB, Bl, A1, bgA, bgB, ln);

    if (t > 0){
      // recurrence edge: per-wave poll (no barrier), then sc1 cache-bypassing
      // A2 loads (poll happens after this step's inv, so plain would be unsafe)
      wpoll(h2f, a32, t, vlh2);
      __builtin_amdgcn_fence(__ATOMIC_ACQUIRE, "workgroup");  // order loads after poll
      const u16* A2 = H2r + (size_t)((t-1)&1)*H_SLOT;
      l2_half<false>(accA, accB, Bl + (size_t)16*4*512, A2, bgA, bgB, ln);
    }

    // epilogue
    float wv[4][5];
    #pragma unroll
    for (int gate=0; gate<4; gate++){
      const float* wp = wlds + (size_t)(gate*16 + col)*6;
      #pragma unroll
      for (int k=0;k<5;k++) wv[gate][k] = wp[k];
    }
    float fcp[2][4];
    #pragma unroll
    for (int sel=0; sel<2; sel++){
      const f32x4* ac = sel ? accB : accA;
      #pragma unroll
      for (int r=0;r<4;r++){
        const float* ip = inp + ((size_t)(bi2*128 + sel*64 + w*16 + quad*4 + r)*T_ + t)*5;
        float i0=ip[0], i1=ip[1], i2=ip[2], i3=ip[3];
        float gv[4];
        #pragma unroll
        for (int gate=0; gate<4; gate++){
          gv[gate] = ac[gate][r] + wv[gate][0]
                   + i0*wv[gate][1] + i1*wv[gate][2] + i2*wv[gate][3] + i3*wv[gate][4];
        }
        float ig=sigm_f(gv[0]), fg=sigm_f(gv[1]), gg=tanh_ff(gv[2]), og=sigm_f(gv[3]);
        float cn = fg*c[sel*4+r] + ig*gg;
        c[sel*4+r] = cn;
        float h = og*tanh_ff(cn);
        fcp[sel][r] = h*fcwr;
        hlds[(size_t)(sel*64 + w*16 + quad*4 + r)*RS + col] = f2bf(h);
      }
    }
    // publish h2[t] FIRST (this is the recurrence edge)
    {
      int sel = ln>>5, ch = (ln>>4)&1, m = ln&15;
      uint4 v = *(const uint4*)&hlds[(size_t)(sel*64 + w*16 + m)*RS + ch*8];
      int lp = ((hj&1)*2 + ch)*16 + m;
      int bgx = bi2*8 + sel*4 + w;
      ring_st16(Hw + (size_t)(t&1)*H_SLOT + ((size_t)(bgx*16 + (hj>>1))*64 + lp)*8, v);
    }
    __syncthreads();   // barrier 2: drains all waves' pack stores before release
    if (tid==0){
      __builtin_amdgcn_fence(__ATOMIC_RELEASE, "workgroup");
      __hip_atomic_store(myf, t+1, __ATOMIC_RELAXED, __HIP_MEMORY_SCOPE_AGENT);
    }

    // fc-out atomics AFTER the flag post (off the critical path)
    #pragma unroll
    for (int sel=0; sel<2; sel++){
      #pragma unroll
      for (int r=0;r<4;r++){
        float v = fcp[sel][r];
        #pragma unroll
        for (int m=1;m<16;m<<=1) v += __shfl_xor(v, m, 16);
        if (col == 0)
          atomicAdd(&out[(size_t)(bi2*128 + sel*64 + w*16 + quad*4 + r)*T_ + t], v);
      }
    }
  }
}

__global__ void __launch_bounds__(256, 1)
lstm_main_v9(const float* __restrict__ inp, const float* __restrict__ W1,
             const float* __restrict__ V1, const float* __restrict__ b1,
             const float* __restrict__ V2, const float* __restrict__ b2,
             const float* __restrict__ fcw, char* __restrict__ ws, float* __restrict__ out)
{
  extern __shared__ char smem[];
  int blk = blockIdx.x;
  if (blk < 128) run_l1(smem, blk, inp, W1, V1, b1, ws);
  else           run_l2(smem, blk-128, inp, V2, b2, fcw, ws, out);
}

extern "C" void kernel_launch(void* const* d_in, const int* in_sizes, int n_in,
                              void* d_out, int out_size, void* d_ws, size_t ws_size,
                              hipStream_t stream) {
  (void)in_sizes; (void)n_in; (void)out_size; (void)ws_size;
  const float* inp = (const float*)d_in[0];
  const float* W1  = (const float*)d_in[1];
  const float* U1  = (const float*)d_in[2];
  const float* V1  = (const float*)d_in[3];
  const float* b1  = (const float*)d_in[4];
  const float* W2  = (const float*)d_in[5];
  const float* U2  = (const float*)d_in[6];
  const float* V2  = (const float*)d_in[7];
  const float* b2  = (const float*)d_in[8];
  const float* fcw = (const float*)d_in[9];
  const float* fcb = (const float*)d_in[10];
  char* ws = (char*)d_ws;
  float* out = (float*)d_out;

  pack_w_kernel<<<1536, 256, 0, stream>>>(U1, W2, U2,
      (u16*)(ws + OFF_U1P), (u16*)(ws + OFF_UW2P));
  init_kernel<<<(B_*T_ + 255)/256, 256, 0, stream>>>(out, fcb, (int*)(ws + OFF_FLAGS));

  (void)hipFuncSetAttribute((const void*)lstm_main_v9,
                            hipFuncAttributeMaxDynamicSharedMemorySize, SMEM_V9);
  lstm_main_v9<<<256, 256, SMEM_V9, stream>>>(inp, W1, V1, b1, V2, b2, fcw, ws, out);
}